// Round 11
// baseline (81.673 us; speedup 1.0000x reference)
//
#include <hip/hip_runtime.h>
#include <math.h>

// EnforceDecrease: two-phase (read-segregated / write-segregated) version.
//   A: ptps = wf.max(T)-wf.min(T); parent-min gather; resc -> ws;
//      decreasing_ptps -> out1.                     (~pure READ stream)
//   B: out0 = wf * resc  (re-read input -- L3-hot from A -- nt-store out). 
//                                                   (~pure WRITE stream)
//
// R6: global_load_lds staging (74.5 -> 65.4). R8: nt stores (-> 55.8).
// R9/R10: persistent pipelines neutral (~56) despite occupancy 39->75% =>
// limiter is NOT intra-kernel overlap; HBM-level 4.4 TB/s vs 6.3 copy
// ceiling + fill@6.9 pure-write => mixed read/write turnaround penalty.
// R11: segregate the streams into two dispatches, each near its pure-stream
// ceiling; B's reads ride L3 (A streamed the whole input immediately prior).

#define N_T 121
#define N_C 40
#define N_P 12
#define TPB 256
#define WF_ELEMS (N_T * N_C)      // 4840 floats
#define WF_QUADS (WF_ELEMS / 4)   // 1210 quads
#define FULL_K   (WF_QUADS / TPB) // 4
#define TAIL_Q   (WF_QUADS - FULL_K * TPB) // 186

typedef float f32x4 __attribute__((ext_vector_type(4)));

#define GLOAD_LDS16(g, l)                                              \
    __builtin_amdgcn_global_load_lds(                                  \
        (const __attribute__((address_space(1))) void*)(g),            \
        (__attribute__((address_space(3))) void*)(l), 16, 0, 0)

// ---------- Kernel A: reduce + gather; read-dominated. ----------
__global__ __launch_bounds__(TPB) void ptps_kernel(
    const float* __restrict__ waveforms,
    const int*   __restrict__ max_channels,
    const int*   __restrict__ parents_index,
    float*       __restrict__ out,
    float*       __restrict__ resc_ws,
    int n_total)
{
    __shared__ float wf[WF_ELEMS];
    __shared__ float pmx[6 * N_C];
    __shared__ float pmn[6 * N_C];
    __shared__ float ptp[N_C];

    const int n   = blockIdx.x;
    const int tid = threadIdx.x;

    const float* src = waveforms + (size_t)n * WF_ELEMS;
    #pragma unroll
    for (int k = 0; k < FULL_K; ++k) {
        const int q = tid + TPB * k;
        GLOAD_LDS16(src + 4 * q, wf + 4 * q);
    }
    if (tid < TAIL_Q) {
        const int q = FULL_K * TPB + tid;
        GLOAD_LDS16(src + 4 * q, wf + 4 * q);
    }
    __syncthreads();   // drains DMA

    if (tid < 6 * N_C) {
        const int ch = tid % N_C;
        const int g  = tid / N_C;
        float mx = -INFINITY, mn = INFINITY;
        for (int t = g; t < N_T; t += 6) {
            const float v = wf[t * N_C + ch];
            mx = fmaxf(mx, v);
            mn = fminf(mn, v);
        }
        pmx[tid] = mx;
        pmn[tid] = mn;
    }
    __syncthreads();

    if (tid < N_C) {
        float mx = pmx[tid], mn = pmn[tid];
        #pragma unroll
        for (int g = 1; g < 6; ++g) {
            mx = fmaxf(mx, pmx[g * N_C + tid]);
            mn = fminf(mn, pmn[g * N_C + tid]);
        }
        ptp[tid] = mx - mn;
    }
    __syncthreads();

    if (tid < N_C) {
        const int  mc   = max_channels[n];
        const int* prow = parents_index + mc * (N_C * N_P) + tid * N_P;
        float minp = INFINITY;
        #pragma unroll
        for (int p = 0; p < N_P; ++p) {
            const int idx = prow[p];
            minp = fminf(minp, (idx >= N_C) ? INFINITY : ptp[idx]);
        }
        const float r = fminf(minp / ptp[tid], 1.0f);
        // resc table for kernel B: normal store (want it cache-resident).
        resc_ws[(size_t)n * N_C + tid] = r;
        // decreasing_ptps, second output.
        __builtin_nontemporal_store(
            ptp[tid] * r,
            out + (size_t)n_total * WF_ELEMS + (size_t)n * N_C + tid);
    }
}

// ---------- Kernel B: streaming scale; write-dominated. ----------
// One block per spike. Input reads should be L3-hits (A just streamed the
// whole input). resc quad (i%10) is L1-resident after first touch.
__global__ __launch_bounds__(TPB) void scale_kernel(
    const float* __restrict__ waveforms,
    const float* __restrict__ resc_ws,
    float*       __restrict__ out)
{
    const int n   = blockIdx.x;
    const int tid = threadIdx.x;

    const f32x4* in4 = (const f32x4*)(waveforms + (size_t)n * WF_ELEMS);
    f32x4*       o4  = (f32x4*)(out + (size_t)n * WF_ELEMS);
    const f32x4* r4  = (const f32x4*)(resc_ws + (size_t)n * N_C); // 10 quads

    // quad i covers channels 4*(i%10) .. +3  ->  resc quad (i%10).
    int m = tid % 10;
    #pragma unroll
    for (int k = 0; k < FULL_K; ++k) {
        const int i = tid + TPB * k;
        const f32x4 s = r4[m];
        f32x4 v = in4[i];
        v.x *= s.x; v.y *= s.y; v.z *= s.z; v.w *= s.w;
        __builtin_nontemporal_store(v, &o4[i]);
        m += 6;                 // (i + 256) % 10 == (m + 6) % 10
        if (m >= 10) m -= 10;
    }
    if (tid < TAIL_Q) {
        const int i = FULL_K * TPB + tid;
        const f32x4 s = r4[m];
        f32x4 v = in4[i];
        v.x *= s.x; v.y *= s.y; v.z *= s.z; v.w *= s.w;
        __builtin_nontemporal_store(v, &o4[i]);
    }
}

extern "C" void kernel_launch(void* const* d_in, const int* in_sizes, int n_in,
                              void* d_out, int out_size, void* d_ws, size_t ws_size,
                              hipStream_t stream) {
    const float* waveforms     = (const float*)d_in[0];
    const int*   max_channels  = (const int*)d_in[1];
    const int*   parents_index = (const int*)d_in[2];
    float*       out           = (float*)d_out;
    float*       resc_ws       = (float*)d_ws;   // N*40 f32 = 1.31 MB

    const int n = in_sizes[1];  // N = 8192

    ptps_kernel<<<dim3(n), dim3(TPB), 0, stream>>>(
        waveforms, max_channels, parents_index, out, resc_ws, n);
    scale_kernel<<<dim3(n), dim3(TPB), 0, stream>>>(
        waveforms, resc_ws, out);
}

// Round 12
// 55.963 us; speedup vs baseline: 1.4594x; 1.4594x over previous
//
#include <hip/hip_runtime.h>
#include <math.h>

// EnforceDecrease: one workgroup per spike n.  (R8 structure == best: 55.8us)
//   ptps = wf.max(T) - wf.min(T)                         (per channel)
//   parent_min = min over P parents of padded ptps       (pad idx c -> +inf)
//   resc = min(parent_min / ptps, 1)
//   out0 = wf * resc[:, None, :]   out1 = ptps * resc
//
// Ladder: 74.5 (float4+LDS) -> 65.4 (global_load_lds DMA staging) ->
// 55.8 (nt stores). R9/R10 persistent pipelines: neutral (~56-58).
// R11 two-phase read/write segregation: 81.7 (extra input read not L3-hit).
// => 55.8us = 5.7 TB/s app-level = 90% of the 6.3 TB/s mixed-stream copy
// ceiling; structural levers exhausted -> this is the practical roofline.

#define N_T 121
#define N_C 40
#define N_P 12
#define TPB 256
#define WF_ELEMS (N_T * N_C)      // 4840 floats
#define WF_QUADS (WF_ELEMS / 4)   // 1210 float4 quads
#define FULL_K   (WF_QUADS / TPB) // 4 full rounds = 1024 quads
#define TAIL_Q   (WF_QUADS - FULL_K * TPB) // 186 tail quads

typedef float f32x4 __attribute__((ext_vector_type(4)));

#define GLOAD_LDS16(g, l)                                              \
    __builtin_amdgcn_global_load_lds(                                  \
        (const __attribute__((address_space(1))) void*)(g),            \
        (__attribute__((address_space(3))) void*)(l), 16, 0, 0)

__global__ __launch_bounds__(TPB) void enforce_decrease_kernel(
    const float* __restrict__ waveforms,
    const int*   __restrict__ max_channels,
    const int*   __restrict__ parents_index,
    float*       __restrict__ out,
    int n_total)
{
    __shared__ float wf[WF_ELEMS];
    __shared__ float pmx[6 * N_C];
    __shared__ float pmn[6 * N_C];
    __shared__ float ptp[N_C];
    __shared__ float resc[N_C];

    const int n   = blockIdx.x;
    const int tid = threadIdx.x;

    // ---- Stage waveform n into LDS via direct global->LDS DMA.
    // LDS layout is linear in lane order (quad i -> LDS byte 16*i), which is
    // exactly the wave-uniform-base + lane*16 pattern the DMA requires.
    const float* src = waveforms + (size_t)n * WF_ELEMS;
    #pragma unroll
    for (int k = 0; k < FULL_K; ++k) {
        const int q = tid + TPB * k;
        GLOAD_LDS16(src + 4 * q, wf + 4 * q);
    }
    if (tid < TAIL_Q) {          // lanes 0..57 of wave 2 active; lane 0 live
        const int q = FULL_K * TPB + tid;
        GLOAD_LDS16(src + 4 * q, wf + 4 * q);
    }
    __syncthreads();             // barrier drains vmcnt -> LDS data ready

    // ---- Per-channel max/min, 6-way split over T.
    // thread = ch + 40*g (g in 0..5); iteration k reads LDS addr 240k+tid
    // -> lane-contiguous, conflict-free.
    if (tid < 6 * N_C) {
        const int ch = tid % N_C;
        const int g  = tid / N_C;
        float mx = -INFINITY, mn = INFINITY;
        for (int t = g; t < N_T; t += 6) {
            const float v = wf[t * N_C + ch];
            mx = fmaxf(mx, v);
            mn = fminf(mn, v);
        }
        pmx[tid] = mx;
        pmn[tid] = mn;
    }
    __syncthreads();

    // ---- Reduce the 6 partials -> ptp per channel.
    if (tid < N_C) {
        float mx = pmx[tid], mn = pmn[tid];
        #pragma unroll
        for (int g = 1; g < 6; ++g) {
            mx = fmaxf(mx, pmx[g * N_C + tid]);
            mn = fminf(mn, pmn[g * N_C + tid]);
        }
        ptp[tid] = mx - mn;
    }
    __syncthreads();

    // ---- Parent-min gather + rescaling + decreasing_ptps output.
    if (tid < N_C) {
        const int  mc   = max_channels[n];
        const int* prow = parents_index + mc * (N_C * N_P) + tid * N_P;
        float minp = INFINITY;
        #pragma unroll
        for (int p = 0; p < N_P; ++p) {
            const int idx = prow[p];
            minp = fminf(minp, (idx >= N_C) ? INFINITY : ptp[idx]);
        }
        const float r = fminf(minp / ptp[tid], 1.0f);
        resc[tid] = r;
        // decreasing_ptps, second output, offset N*T*c -- nt store
        __builtin_nontemporal_store(
            ptp[tid] * r,
            out + (size_t)n_total * WF_ELEMS + (size_t)n * N_C + tid);
    }
    __syncthreads();

    // ---- Rescaled waveform from LDS, non-temporal 16B stores.
    // 40 % 4 == 0 -> channels of one quad are ch0..ch0+3, never wrapping.
    const f32x4* wf4  = (const f32x4*)wf;
    f32x4*       dst4 = (f32x4*)(out + (size_t)n * WF_ELEMS);
    #pragma unroll
    for (int i = tid; i < WF_QUADS; i += TPB) {
        f32x4 v = wf4[i];
        const int ch0 = (i * 4) % N_C;
        v.x *= resc[ch0];
        v.y *= resc[ch0 + 1];
        v.z *= resc[ch0 + 2];
        v.w *= resc[ch0 + 3];
        __builtin_nontemporal_store(v, &dst4[i]);
    }
}

extern "C" void kernel_launch(void* const* d_in, const int* in_sizes, int n_in,
                              void* d_out, int out_size, void* d_ws, size_t ws_size,
                              hipStream_t stream) {
    const float* waveforms     = (const float*)d_in[0];
    const int*   max_channels  = (const int*)d_in[1];
    const int*   parents_index = (const int*)d_in[2];
    float*       out           = (float*)d_out;

    const int n = in_sizes[1];  // N = 8192 (element count of max_channels)

    enforce_decrease_kernel<<<dim3(n), dim3(TPB), 0, stream>>>(
        waveforms, max_channels, parents_index, out, n);
}